// Round 8
// baseline (1942.354 us; speedup 1.0000x reference)
//
#include <hip/hip_runtime.h>

// ---------------------------------------------------------------------------
// MTSLTM (time-aware LSTM), B=64 T=512 D=256 H=512 — round 8.
// Persistent kernel: 64 blocks x 512 threads (8 waves), 1 block/CU.
// Grid: 4 batch-groups (16 batches) x 16 col-slices (32 h-cols = 128 g-cols).
// vs r7:
//  * PER-WAVE flag protocol: wave wv's cell covers batches (2wv,2wv+1); after
//    barrier B it stores its h/c slice (sc1), drains wave-locally (vmcnt(0)),
//    posts sub-flag flags[bid*8+wv]. Consumers poll 16 sub-flags. Sync C and
//    the full-block drain are GONE (2 barriers/step).
//  * Gate/Wd partials in stride-5 scalar LDS layouts ([8][320] f32): both the
//    writes (ln*5 mod 32 bijective) and the cell reads (broadcast across
//    half-waves) are bank-conflict-free — r7's 50M conflict cycles targeted.
//  * xgemm pre-B (required: no barrier between B and next A to protect x_lds).
//  * plain inp loads (L3-shared by 16 blocks); plain out stores (fast ack).
// ---------------------------------------------------------------------------

constexpr int kB = 64, kT = 512, kD = 256, kH = 512, kG = 2048;
constexpr int NBLK = 64, NTHR = 512;
constexpr int BPG  = 16;   // batches per group

typedef __attribute__((ext_vector_type(8))) short short8v;   // 8 bf16
typedef __attribute__((ext_vector_type(4))) float f32x4;
typedef __attribute__((ext_vector_type(4))) unsigned int uint4v;

__device__ __forceinline__ float fsig(float x)  { return 1.0f / (1.0f + __expf(-x)); }
__device__ __forceinline__ float ftanh(float x) { return 2.0f / (1.0f + __expf(-2.0f * x)) - 1.0f; }
__device__ __forceinline__ unsigned short f2bf(float f) {    // RNE f32->bf16
  unsigned u = __float_as_uint(f);
  return (unsigned short)((u + 0x7FFFu + ((u >> 16) & 1u)) >> 16);
}
__device__ __forceinline__ unsigned pk2(float a, float b) {
  return (unsigned)f2bf(a) | ((unsigned)f2bf(b) << 16);
}

__global__ __launch_bounds__(NTHR, 2) void mtsltm_kernel(
    const float* __restrict__ inp, const float* __restrict__ tdel,
    const float* __restrict__ Wd,  const float* __restrict__ W,
    const float* __restrict__ U,   const float* __restrict__ bias,
    float* __restrict__ out,
    unsigned* __restrict__ hb32, unsigned* __restrict__ cb32,
    unsigned* __restrict__ flags)
{
  // 60.5 KB LDS. h/c/x XOR-swizzled in 16B units (unit' = unit ^ (row&7)).
  __shared__ __align__(16) unsigned short h_lds[16][512];  // 16 KB
  __shared__ __align__(16) unsigned short c_lds[16][512];  // 16 KB
  __shared__ __align__(16) unsigned short x_lds[16][256];  // 8 KB
  __shared__ float g5[8][320];   // gate tiles, stride-5: [tile][lane*5+reg]
  __shared__ float s5[8][320];   // Wd partials, stride-5

  const int tid = threadIdx.x, bid = blockIdx.x;
  const int bg = bid & 3;          // batch group (16-block sync group)
  const int cs = bid >> 2;         // col slice [0,16)
  const int wv = tid >> 6, ln = tid & 63;
  const int lm = ln & 15, lg = ln >> 4;   // MFMA lane decomposition

  // ---------------- one-time: weights -> VGPRs (bf16 B-fragments) -----------
  const int gcol = (wv >> 1) * kH + cs * 32 + (wv & 1) * 16 + lm;
  short8v bU[16];                                   // U[512][gcol]
  #pragma unroll
  for (int kt = 0; kt < 16; ++kt) {
    short8v v;
    #pragma unroll
    for (int e = 0; e < 8; ++e)
      v[e] = (short)f2bf(U[(size_t)(kt * 32 + lg * 8 + e) * kG + gcol]);
    bU[kt] = v;
  }
  short8v bX[8];                                    // W[256][gcol]
  #pragma unroll
  for (int kt = 0; kt < 8; ++kt) {
    short8v v;
    #pragma unroll
    for (int e = 0; e < 8; ++e)
      v[e] = (short)f2bf(W[(size_t)(kt * 32 + lg * 8 + e) * kG + gcol]);
    bX[kt] = v;
  }
  const int kq = wv >> 1, ns = wv & 1;   // Wd: k-quarter kq, n-tile ns
  short8v bWd[4];
  #pragma unroll
  for (int kt = 0; kt < 4; ++kt) {
    short8v v;
    #pragma unroll
    for (int e = 0; e < 8; ++e)
      v[e] = (short)f2bf(Wd[(size_t)(kq * 128 + kt * 32 + lg * 8 + e) * kH
                            + cs * 32 + ns * 16 + lm]);
    bWd[kt] = v;
  }
  const float bias_r = bias[gcol];

  // ---------------- identities ----------------
  const int r = tid & 15, ch = tid >> 4, rs = r & 7;   // x staging
  const int bgl_r = bg * BPG + r;
  const int row2 = ln >> 2, q = ln & 3;                // h/c staging (per wave)
  const int cm = tid >> 5, cj = tid & 31;              // cell: batch cm = 2wv+(ln>>5)
  const int idxr = (cj & 15) + 16 * (wv >> 1);         // D-frag lane index
  const int jr = cm & 3, chf = cj >> 4;
  const size_t bglc = (size_t)bg * BPG + cm;
  const int colg = cs * 32 + cj;
  float c_keep = 0.0f;                                 // exact f32 cell carry
  const size_t HID = (size_t)kB * kT * kH;

  auto xgemm = [&]() -> f32x4 {    // x-part of next step's gates (+bias)
    f32x4 a = {bias_r, bias_r, bias_r, bias_r};
    #pragma unroll
    for (int kt = 0; kt < 8; ++kt) {
      short8v av = *(const short8v*)&x_lds[lm][((kt * 4 + lg) ^ (lm & 7)) * 8];
      a = __builtin_amdgcn_mfma_f32_16x16x32_bf16(av, bX[kt], a, 0, 0, 0);
    }
    return a;
  };

  // ---------------- prologue ----------------
  {  // stage x[0]
    const float* xs = inp + ((size_t)bgl_r * kT + 0) * kD + ch * 8;
    float4 a = *(const float4*)xs, b = *(const float4*)(xs + 4);
    uint4v xv;
    xv.x = pk2(a.x, a.y); xv.y = pk2(a.z, a.w);
    xv.z = pk2(b.x, b.y); xv.w = pk2(b.z, b.w);
    *(uint4v*)&x_lds[r][(ch ^ rs) * 8] = xv;
  }
  float4 xa, xb;
  {  // prefetch x[1]
    const float* xs = inp + ((size_t)bgl_r * kT + 1) * kD + ch * 8;
    xa = *(const float4*)xs; xb = *(const float4*)(xs + 4);
  }
  float tdv = tdel[bglc * kT + 0];
  __syncthreads();
  f32x4 xacc = xgemm();
  __syncthreads();   // protect x_lds before t=0's stage phase

  for (int t = 0; t < kT; ++t) {
    // ---------------- phase 1: per-wave poll + h/c stage (sc1) --------------
    if (t > 0) {
      // wave wv consumes k-cols [64wv,64wv+64) = producer slices 2wv, 2wv+1.
      // poll their 16 sub-flags (8 per block) with lanes 0..15.
      const unsigned* fp = flags +
          ((((2 * wv + ((ln >> 3) & 1)) * 4 + bg) * 8) + (ln & 7)) * 32;
      int spins = 0;
      for (;;) {
        unsigned v = (ln < 16)
            ? __hip_atomic_load(fp, __ATOMIC_RELAXED, __HIP_MEMORY_SCOPE_AGENT)
            : 0xFFFFFFFFu;
        if (__all(v >= (unsigned)t)) break;
        if (++spins > (1 << 20)) break;   // safety valve
      }
      __atomic_signal_fence(__ATOMIC_ACQUIRE);
      const size_t rb = ((size_t)((t - 1) & 1) * kB + bg * 16 + row2) * 256
                        + (2 * wv) * 16 + q * 4;
      const unsigned* hsrc = hb32 + rb;
      const unsigned* csrc = cb32 + rb;
      uint4v h0, h1, c0, c1;
      asm volatile(
        "global_load_dwordx4 %0, %4, off sc1\n\t"
        "global_load_dwordx4 %1, %4, off offset:64 sc1\n\t"
        "global_load_dwordx4 %2, %5, off sc1\n\t"
        "global_load_dwordx4 %3, %5, off offset:64 sc1"
        : "=&v"(h0), "=&v"(h1), "=&v"(c0), "=&v"(c1)
        : "v"(hsrc), "v"(csrc));
      asm volatile("s_waitcnt vmcnt(0)" ::: "memory");
      __builtin_amdgcn_sched_barrier(0);
      const int rsw = row2 & 7;
      *(uint4v*)&h_lds[row2][((8 * wv + q)     ^ rsw) * 8] = h0;
      *(uint4v*)&h_lds[row2][((8 * wv + 4 + q) ^ rsw) * 8] = h1;
      *(uint4v*)&c_lds[row2][((8 * wv + q)     ^ rsw) * 8] = c0;
      *(uint4v*)&c_lds[row2][((8 * wv + 4 + q) ^ rsw) * 8] = c1;
    }
    if (t + 1 < kT) {   // stage x[t+1] from prefetched regs
      uint4v xv;
      xv.x = pk2(xa.x, xa.y); xv.y = pk2(xa.z, xa.w);
      xv.z = pk2(xb.x, xb.y); xv.w = pk2(xb.z, xb.w);
      *(uint4v*)&x_lds[r][(ch ^ rs) * 8] = xv;
    }
    __syncthreads();                                   // barrier A

    // ---------------- phase 2: h@U (C-in=xacc) + c@Wd + xgemm(t+1) ----------
    if (t > 0) {
      f32x4 a0 = xacc, a1 = {0.f, 0.f, 0.f, 0.f};
      #pragma unroll
      for (int kt = 0; kt < 8; ++kt) {
        short8v av = *(const short8v*)&h_lds[lm][((kt * 4 + lg) ^ (lm & 7)) * 8];
        a0 = __builtin_amdgcn_mfma_f32_16x16x32_bf16(av, bU[kt], a0, 0, 0, 0);
      }
      #pragma unroll
      for (int kt = 8; kt < 16; ++kt) {
        short8v av = *(const short8v*)&h_lds[lm][((kt * 4 + lg) ^ (lm & 7)) * 8];
        a1 = __builtin_amdgcn_mfma_f32_16x16x32_bf16(av, bU[kt], a1, 0, 0, 0);
      }
      f32x4 aw = {0.f, 0.f, 0.f, 0.f};
      #pragma unroll
      for (int kt = 0; kt < 4; ++kt) {
        short8v av = *(const short8v*)&c_lds[lm][((kq * 16 + kt * 4 + lg) ^ (lm & 7)) * 8];
        aw = __builtin_amdgcn_mfma_f32_16x16x32_bf16(av, bWd[kt], aw, 0, 0, 0);
      }
      #pragma unroll
      for (int j = 0; j < 4; ++j) {
        g5[wv][ln * 5 + j] = a0[j] + a1[j];
        s5[wv][ln * 5 + j] = aw[j];
      }
    } else {
      #pragma unroll
      for (int j = 0; j < 4; ++j) g5[wv][ln * 5 + j] = xacc[j];
    }
    if (t + 1 < kT) xacc = xgemm();   // must be pre-B (x_lds hazard window)
    __syncthreads();                                   // barrier B

    // ---------------- phase 3: cell + per-wave store/drain/flag -------------
    {
      float g0 = g5[0 + chf][idxr * 5 + jr];
      float g1 = g5[2 + chf][idxr * 5 + jr];
      float g2 = g5[4 + chf][idxr * 5 + jr];
      float g3 = g5[6 + chf][idxr * 5 + jr];
      float sw = 0.f;
      if (t > 0) {
        #pragma unroll
        for (int q2 = 0; q2 < 4; ++q2) sw += s5[2 * q2 + chf][idxr * 5 + jr];
      }
      float csv  = ftanh(sw);
      float cadj = (c_keep - csv) + csv / __logf(2.71828182845904523536f + tdv);
      float gi = fsig(g0), gf = fsig(g1), gg = ftanh(g2), go = fsig(g3);
      float cnew = fmaf(gf, cadj, gi * gg);
      float tcn  = ftanh(cnew);          // = c_out
      float hout = ftanh(go * tcn);      // = tanh(o * tanh(c_new))
      c_keep = tcn;
      out[(bglc * kT + t) * kH + colg] = hout;
      if (t == kT - 1) {
        out[HID + bglc * kH + colg] = hout;                      // h_t
        out[HID + (size_t)kB * kH + bglc * kH + colg] = tcn;     // c_t
      }
      float h2 = __shfl_xor(hout, 1), c2 = __shfl_xor(tcn, 1);
      if (!(cj & 1)) {
        unsigned hp = pk2(hout, h2), cp = pk2(tcn, c2);
        size_t di = ((size_t)(t & 1) * kB + bglc) * 256 + (colg >> 1);
        __hip_atomic_store(hb32 + di, hp, __ATOMIC_RELAXED, __HIP_MEMORY_SCOPE_AGENT);
        __hip_atomic_store(cb32 + di, cp, __ATOMIC_RELAXED, __HIP_MEMORY_SCOPE_AGENT);
      }
      // wave-local drain: this wave's out + h/c stores are at their
      // coherence points; then publish this wave's sub-flag.
      asm volatile("s_waitcnt vmcnt(0)" ::: "memory");
      if (ln == 0)
        __hip_atomic_store(&flags[(bid * 8 + wv) * 32], (unsigned)(t + 1),
                           __ATOMIC_RELAXED, __HIP_MEMORY_SCOPE_AGENT);
    }

    // ---------------- shadow work (overlaps other blocks' progress) ---------
    if (t + 2 < kT) {
      const float* xs = inp + ((size_t)bgl_r * kT + (t + 2)) * kD + ch * 8;
      xa = *(const float4*)xs; xb = *(const float4*)(xs + 4);
    }
    if (t + 1 < kT) tdv = tdel[bglc * kT + (t + 1)];
  }
}

extern "C" void kernel_launch(void* const* d_in, const int* in_sizes, int n_in,
                              void* d_out, int out_size, void* d_ws, size_t ws_size,
                              hipStream_t stream)
{
  const float* inp  = (const float*)d_in[0];
  const float* td   = (const float*)d_in[1];
  const float* Wd   = (const float*)d_in[2];
  const float* W    = (const float*)d_in[3];
  const float* U    = (const float*)d_in[4];
  const float* bias = (const float*)d_in[5];
  float* out = (float*)d_out;

  // ws: hb[2][64][256]u32 (128KB) | cb (128KB) | flags 64*8*32 u32 (64KB)
  unsigned* hb32  = (unsigned*)d_ws;
  unsigned* cb32  = hb32 + (size_t)2 * kB * 256;
  unsigned* flags = cb32 + (size_t)2 * kB * 256;

  (void)hipMemsetAsync(flags, 0, NBLK * 8 * 32 * sizeof(unsigned), stream);
  mtsltm_kernel<<<dim3(NBLK), dim3(NTHR), 0, stream>>>(inp, td, Wd, W, U, bias,
                                                       out, hb32, cb32, flags);
}